// Round 4
// baseline (82.290 us; speedup 1.0000x reference)
//
#include <hip/hip_runtime.h>
#include <cstdint>
#include <cstddef>
#include <utility>

// ---------------------------------------------------------------------------
// out[8192,32] = x + P(x)[8192,6545] @ W[6545,32]
// v10: v7's fast loop, single kernel via device-scope counter barrier.
//   Grid 256 x 512thr (1 block/mtile, all co-resident: 256 blocks <= 256 CUs,
//   launch_bounds(512,2) guarantees fit -> spin barrier cannot deadlock).
//   Each block: (a) writes its 112 Wh octets (256*112 = 28672 exact cover),
//   (b) __syncthreads + leader RELEASE atomicAdd on persistent __device__
//   counter, (c) phase-1 t/xd LDS build (overlaps other blocks' prep),
//   (d) lane-0 ACQUIRE-spin until counter >= epoch+256 (epoch recovered
//   wrap-safely: each block reads ctr BEFORE its own add, so r <= start+255
//   and (r & ~255) = start; compare via (int32)(cur-target) >= 0),
//   (e) v7's unchanged 8-deep rotating pipeline (56 steps/wave, dual acc),
//   (f) 8-bank LDS reduce epilogue, out = x + acc.
//   vs v7: deletes the prep dispatch + inter-dispatch gap; W-gather latency
//   hides under phase-1. Numerics bit-identical to v7 (same gather, RTN
//   f32->f16, same MFMA order).
// ---------------------------------------------------------------------------

#define NF 32
#define NPOLY 6545
#define NSTEPS 448          // K = 7168 = 448*16 (zero-padded from 6545)
#define NDESC 1024          // zero-padded (toff=0/xoff=0 -> safe addresses)
#define CHUNK 56            // steps per wave (8 chunks x 56 = 448)
#define TSTRIDE 576         // halfs per t-row (72 octets, 1152 B)
#define D2OFF 40            // d2 base index inside t (8-aligned)
#define XDSTRIDE 34         // halfs per xdup row (68 B)

#define XD_OFF    36864     // t = 32*576*2 bytes
#define SMEM_BYTES 39040    // t + xd

typedef _Float16 f16x8 __attribute__((ext_vector_type(8)));
typedef float f32x16 __attribute__((ext_vector_type(16)));
typedef short short8v __attribute__((ext_vector_type(8)));

// Persistent cross-launch barrier counter (zero-init at module load; epoch
// arithmetic below is correct across graph replays and at uint32 wrap since
// 2^32 % 256 == 0).
__device__ uint32_t g_whctr = 0u;

#define D2N 528
struct D2I { uint8_t a[D2N]; uint8_t b[D2N]; };
constexpr D2I build_d2i() {
    D2I t{};
    int k = 0;
    for (int f = 0; f < NF; ++f)
        for (int m = 0; m <= f; ++m) { t.a[k] = (uint8_t)f; t.b[k] = (uint8_t)m; ++k; }
    return t;
}
constexpr D2I D2T = build_d2i();

// Descriptor per half-octet: low16 = t byte offset (16B aligned), high16 = xd
// byte offset (xidx*2; xidx 0 -> 1.0, 1+f -> x_f). Zero-padded to NDESC.
struct Desc { uint32_t d[NDESC]; };
constexpr Desc build_desc() {
    Desc D{};
    int u = 0;
    for (int o = 0; o < 72; ++o)                       // segA: direct t octets
        D.d[u++] = (uint32_t)(o * 16);
    for (int f = 0; f < NF; ++f) {                     // segB: x_f * d2 octets
        int cnt = (f + 1) * (f + 2) / 2;
        for (int j8 = 0; j8 < (cnt + 7) / 8; ++j8)
            D.d[u++] = (uint32_t)((D2OFF + 8 * j8) * 2) | ((uint32_t)((1 + f) * 2) << 16);
    }
    while (u < NDESC) D.d[u++] = 0u;                   // pad: t[0..7] * xd[0]
    return D;
}
__device__ const Desc DESC_G = build_desc();

// Map new K index -> original monomial index (or -1 = zero W row).
struct Oldk { int16_t v[NSTEPS * 16]; };
constexpr Oldk build_oldk() {
    Oldk K{};
    int k = 0;
    for (int ti = 0; ti < 576; ++ti) {                 // segA
        int old;
        if (ti == 0) old = 0;
        else if (ti <= 32) old = ti;
        else if (ti >= D2OFF && ti < D2OFF + D2N) old = 33 + (ti - D2OFF);
        else old = -1;
        K.v[k++] = (int16_t)old;
    }
    for (int f = 0; f < NF; ++f) {                     // segB
        int cnt = (f + 1) * (f + 2) / 2;
        int off3 = 0;
        for (int g = 0; g < f; ++g) off3 += (g + 1) * (g + 2) / 2;
        int oc = (cnt + 7) / 8;
        for (int m = 0; m < oc * 8; ++m)
            K.v[k++] = (int16_t)(m < cnt ? 561 + off3 + m : -1);
    }
    while (k < NSTEPS * 16) K.v[k++] = (int16_t)-1;    // pad steps: zero W
    return K;
}
__device__ const Oldk OLDK_G = build_oldk();

// ---- phase-1 helpers ----
template<int TI>
__device__ __forceinline__ _Float16 tval(const float (&xr)[NF]) {
    if constexpr (TI == 0) return (_Float16)1.0f;
    else if constexpr (TI >= 1 && TI <= 32) return (_Float16)xr[TI - 1];
    else if constexpr (TI >= D2OFF && TI < D2OFF + D2N) {
        constexpr int m = TI - D2OFF;
        return (_Float16)(xr[D2T.a[m]] * xr[D2T.b[m]]);
    } else return (_Float16)0.0f;
}

template<int O, int... Js>
__device__ __forceinline__ void put_oct(std::integer_sequence<int, Js...>,
                                        const float (&xr)[NF], _Float16* trow, int r) {
    f16x8 v = { tval<O * 8 + Js>(xr)... };
    int slot = (O & ~7) | ((O ^ r) & 7);               // XOR swizzle (16B granule)
    *(f16x8*)(trow + slot * 8) = v;
}

template<int BASE, int... Os>
__device__ __forceinline__ void p1_octs(std::integer_sequence<int, Os...>,
                                        const float (&xr)[NF], _Float16* trow, int r) {
    (put_oct<BASE + Os>(std::make_integer_sequence<int, 8>{}, xr, trow, r), ...);
}

template<int V>
__device__ __forceinline__ void xdw(const float (&xr)[NF], _Float16* xdrow) {
    if constexpr (V == 0) xdrow[0] = (_Float16)1.0f;
    else if constexpr (V <= 32) xdrow[V] = (_Float16)xr[V - 1];
}

template<int G>
__device__ __forceinline__ void p1_group(const float (&xr)[NF], _Float16* trow,
                                         _Float16* xdrow, int r) {
    if constexpr (G < 8)
        p1_octs<G * 5>(std::make_integer_sequence<int, 5>{}, xr, trow, r);
    else
        p1_octs<40 + (G - 8) * 4>(std::make_integer_sequence<int, 4>{}, xr, trow, r);
    xdw<2 * G>(xr, xdrow);
    xdw<2 * G + 1>(xr, xdrow);
    if constexpr (G == 15) xdw<32>(xr, xdrow);
}

__global__ __launch_bounds__(512, 2) void fused(const float* __restrict__ x,
                                                const float* __restrict__ W,
                                                _Float16* __restrict__ Wh,
                                                float* __restrict__ out) {
    __shared__ __align__(16) unsigned char smem[SMEM_BYTES];
    _Float16* t  = (_Float16*)smem;
    _Float16* xd = (_Float16*)(smem + XD_OFF);

    const int tid = threadIdx.x;
    const int wave = __builtin_amdgcn_readfirstlane(tid >> 6);
    const int lane = tid & 63;
    const int hsel = lane >> 5, r = lane & 31;
    const int mtile = blockIdx.x;

    // ---- epoch read: MUST precede this block's own add (program order on
    // tid 0 guarantees it). r0 <= epoch_start + 255 -> (r0 & ~255) = start.
    uint32_t target = 0u;
    if (tid == 0) {
        uint32_t r0 = __hip_atomic_load(&g_whctr, __ATOMIC_RELAXED,
                                        __HIP_MEMORY_SCOPE_AGENT);
        target = (r0 & ~255u) + 256u;
    }

    // ---- prep part: this block's 112 Wh octets (28672 = 256 * 112) ----
    if (tid < 112) {
        int id = mtile * 112 + tid;
        int step = id >> 6, rem = id & 63, hs = rem >> 5, n = rem & 31;
        int k0 = step * 16 + hs * 8;
        short8v olds = *(const short8v*)(OLDK_G.v + k0);   // one 16B load
        f16x8 v;
#pragma unroll
        for (int j = 0; j < 8; ++j) {
            int old = olds[j];
            v[j] = (_Float16)(old >= 0 ? W[old * 32 + n] : 0.0f);
        }
        *(f16x8*)(Wh + (size_t)id * 8) = v;
    }

    // ---- publish: all block stores done -> leader RELEASE add ----
    __syncthreads();
    if (tid == 0)
        __hip_atomic_fetch_add(&g_whctr, 1u, __ATOMIC_RELEASE,
                               __HIP_MEMORY_SCOPE_AGENT);

    // ---- phase 1: t (swizzled) + xdup (overlaps other blocks' prep) ----
    {
        const int pr = tid & 31, g = tid >> 5;         // 16 workers per row
        float xr[NF];
        const float4* xp = (const float4*)(x + (size_t)(mtile * 32 + pr) * NF);
#pragma unroll
        for (int i = 0; i < 8; ++i) {
            float4 v = xp[i];
            xr[4 * i + 0] = v.x; xr[4 * i + 1] = v.y;
            xr[4 * i + 2] = v.z; xr[4 * i + 3] = v.w;
        }
        _Float16* trow = t + pr * TSTRIDE;
        _Float16* xdrow = xd + pr * XDSTRIDE;
        switch (g) {
            case  0: p1_group< 0>(xr, trow, xdrow, pr); break;
            case  1: p1_group< 1>(xr, trow, xdrow, pr); break;
            case  2: p1_group< 2>(xr, trow, xdrow, pr); break;
            case  3: p1_group< 3>(xr, trow, xdrow, pr); break;
            case  4: p1_group< 4>(xr, trow, xdrow, pr); break;
            case  5: p1_group< 5>(xr, trow, xdrow, pr); break;
            case  6: p1_group< 6>(xr, trow, xdrow, pr); break;
            case  7: p1_group< 7>(xr, trow, xdrow, pr); break;
            case  8: p1_group< 8>(xr, trow, xdrow, pr); break;
            case  9: p1_group< 9>(xr, trow, xdrow, pr); break;
            case 10: p1_group<10>(xr, trow, xdrow, pr); break;
            case 11: p1_group<11>(xr, trow, xdrow, pr); break;
            case 12: p1_group<12>(xr, trow, xdrow, pr); break;
            case 13: p1_group<13>(xr, trow, xdrow, pr); break;
            case 14: p1_group<14>(xr, trow, xdrow, pr); break;
            default: p1_group<15>(xr, trow, xdrow, pr); break;
        }
    }

    // ---- per-wave descriptor preload (lane = step - s0; indices 0..63 used) ----
    const int s0 = __builtin_amdgcn_readfirstlane(wave * CHUNK);
    uint32_t vD0 = DESC_G.d[2 * (s0 + lane)];          // max idx 2*(392+63)=910 < 1024
    uint32_t vD1 = DESC_G.d[2 * (s0 + lane) + 1];

    __syncthreads();                                   // t/xd ready (block-local)

    // ---- wait for all 256 blocks' Wh (ACQUIRE; wrap-safe compare) ----
    if (tid == 0) {
        uint32_t cur;
        do {
            __builtin_amdgcn_s_sleep(2);
            cur = __hip_atomic_load(&g_whctr, __ATOMIC_ACQUIRE,
                                    __HIP_MEMORY_SCOPE_AGENT);
        } while ((int32_t)(cur - target) < 0);
    }
    __syncthreads();                                   // release whole block

    const char* trowB = (const char*)t + r * (TSTRIDE * 2);
    const char* xdrowB = (const char*)xd + r * (XDSTRIDE * 2);
    const char* wpB = (const char*)Wh + lane * 16;     // + s*1024 per step
    const uint32_t rx = (uint32_t)((r & 7) << 4);

    f32x16 acc0, acc1;
#pragma unroll
    for (int i = 0; i < 16; ++i) { acc0[i] = 0.0f; acc1[i] = 0.0f; }

#define DSEL(IDX) (hsel ? __builtin_amdgcn_readlane(vD1, (IDX)) \
                        : __builtin_amdgcn_readlane(vD0, (IDX)))

    f16x8 araw0, araw1, araw2, araw3, araw4, araw5, araw6, araw7;
    f16x8 breg0, breg1, breg2, breg3, breg4, breg5, breg6, breg7;
    _Float16 xs0, xs1, xs2, xs3, xs4, xs5, xs6, xs7;

#define LOADSLOT(P, IDX) do {                                                 \
    uint32_t d_ = DSEL(IDX);                                                  \
    araw##P = *(const f16x8*)(trowB + ((d_ & 0xffffu) ^ rx));                 \
    xs##P   = *(const _Float16*)(xdrowB + (d_ >> 16));                        \
    breg##P = *(const f16x8*)(wpB + (size_t)(s0 + (IDX)) * 1024);             \
} while (0)

    LOADSLOT(0, 0); LOADSLOT(1, 1); LOADSLOT(2, 2); LOADSLOT(3, 3);
    LOADSLOT(4, 4); LOADSLOT(5, 5); LOADSLOT(6, 6); LOADSLOT(7, 7);

#define BODY(P, IDX, A) do {                                                  \
    f16x8 xsv_ = { xs##P, xs##P, xs##P, xs##P, xs##P, xs##P, xs##P, xs##P };  \
    f16x8 a_ = araw##P * xsv_;                                                \
    f16x8 bu_ = breg##P;                                                      \
    LOADSLOT(P, (IDX) + 8);  /* prefetch 8 ahead; pads/over-reads are safe */ \
    A = __builtin_amdgcn_mfma_f32_32x32x16_f16(a_, bu_, A, 0, 0, 0);          \
} while (0)

#pragma unroll
    for (int i = 0; i < 7; ++i) {
        BODY(0, 8 * i + 0, acc0);
        BODY(1, 8 * i + 1, acc1);
        BODY(2, 8 * i + 2, acc0);
        BODY(3, 8 * i + 3, acc1);
        BODY(4, 8 * i + 4, acc0);
        BODY(5, 8 * i + 5, acc1);
        BODY(6, 8 * i + 6, acc0);
        BODY(7, 8 * i + 7, acc1);
    }
#undef BODY
#undef LOADSLOT
#undef DSEL

#pragma unroll
    for (int i = 0; i < 16; ++i) acc0[i] += acc1[i];

    // ---- epilogue: 8-bank LDS reduce (aliased over t), add x, plain store ----
    __syncthreads();                                   // all waves done with t/xd
    float* red = (float*)smem;                         // 8 * 4096 B = 32768 B
    float* bank = red + wave * 1024;
#pragma unroll
    for (int reg = 0; reg < 16; ++reg) {
        int rr = (reg & 3) + 8 * (reg >> 2) + 4 * hsel;  // C/D row
        bank[rr * 32 + r] = acc0[reg];
    }
    __syncthreads();
    const float* xt = x + (size_t)mtile * 1024;
    float* op = out + (size_t)mtile * 1024;
#pragma unroll
    for (int i = 0; i < 2; ++i) {
        int e = tid + i * 512;
        float v = red[e] + red[1024 + e] + red[2048 + e] + red[3072 + e]
                + red[4096 + e] + red[5120 + e] + red[6144 + e] + red[7168 + e]
                + xt[e];
        op[e] = v;
    }
}

extern "C" void kernel_launch(void* const* d_in, const int* in_sizes, int n_in,
                              void* d_out, int out_size, void* d_ws, size_t ws_size,
                              hipStream_t stream) {
    (void)in_sizes; (void)n_in; (void)out_size; (void)ws_size;
    const float* x = (const float*)d_in[0];   // [8192,32]
    const float* W = (const float*)d_in[1];   // [6545,32]
    float* out = (float*)d_out;               // [8192,32]
    _Float16* Wh = (_Float16*)d_ws;           // ~467 KB of d_ws used (incl over-read)

    fused<<<256, 512, 0, stream>>>(x, W, Wh, out);
}

// Round 5
// 67.491 us; speedup vs baseline: 1.2193x; 1.2193x over previous
//
#include <hip/hip_runtime.h>
#include <cstdint>
#include <cstddef>
#include <utility>

// ---------------------------------------------------------------------------
// out[8192,32] = x + P(x)[8192,6545] @ W[6545,32]
// v11 = v7 (the measured-best structure, 67.9us round 1), reverted after
// v8 (coop grid.sync: +37us spin), v9 (no-ws in-loop gather: +5us loop),
// v10 (counter barrier: +14us cross-XCD atomics) all regressed.
//   Grid 256 x 512thr (1 block/mtile, 8 waves/CU). Each wave owns 56 steps
//   (448 = 8*56). No atomics: epilogue reduces 8 waves in LDS, adds x, and
//   plain-stores out. prep builds Wh only (112 blocks; OLDK read as short8).
//   Pipeline is 8-slot rotating (prefetch 8 ahead, ~360 cyc slack covers
//   LDS ~120 / L2 ~200 at 2 waves/SIMD); dual accumulators (acc0/acc1)
//   break the serial MFMA dependency chain. __launch_bounds__(512,2) ->
//   VGPR cap 256 (~125 used). Numerics identical to v6/v7 (f16 RTN, f32 acc).
// Ledger (measured): dur ~= 40.3 (unconditional ws poison fill, 83% HBM)
//   + ~20 (harness resets/launch gaps, structure-invariant) + ~7 (kernels).
// ---------------------------------------------------------------------------

#define NF 32
#define NPOLY 6545
#define NSTEPS 448          // K = 7168 = 448*16 (zero-padded from 6545)
#define NREAL 417           // steps with any real data (417*16 = 6672)
#define NOCT 834            // real half-octet descriptors
#define NDESC 1024          // zero-padded (toff=0/xoff=0 -> safe addresses)
#define CHUNK 56            // steps per wave (8 chunks x 56 = 448)
#define TSTRIDE 576         // halfs per t-row (72 octets, 1152 B)
#define D2OFF 40            // d2 base index inside t (8-aligned)
#define XDSTRIDE 34         // halfs per xdup row (68 B)

#define XD_OFF    36864     // t = 32*576*2 bytes
#define SMEM_BYTES 39040    // t + xd

typedef _Float16 f16x8 __attribute__((ext_vector_type(8)));
typedef float f32x16 __attribute__((ext_vector_type(16)));
typedef short short8v __attribute__((ext_vector_type(8)));

#define D2N 528
struct D2I { uint8_t a[D2N]; uint8_t b[D2N]; };
constexpr D2I build_d2i() {
    D2I t{};
    int k = 0;
    for (int f = 0; f < NF; ++f)
        for (int m = 0; m <= f; ++m) { t.a[k] = (uint8_t)f; t.b[k] = (uint8_t)m; ++k; }
    return t;
}
constexpr D2I D2T = build_d2i();

// Descriptor per half-octet: low16 = t byte offset (16B aligned), high16 = xd
// byte offset (xidx*2; xidx 0 -> 1.0, 1+f -> x_f). Zero-padded to NDESC.
struct Desc { uint32_t d[NDESC]; };
constexpr Desc build_desc() {
    Desc D{};
    int u = 0;
    for (int o = 0; o < 72; ++o)                       // segA: direct t octets
        D.d[u++] = (uint32_t)(o * 16);
    for (int f = 0; f < NF; ++f) {                     // segB: x_f * d2 octets
        int cnt = (f + 1) * (f + 2) / 2;
        for (int j8 = 0; j8 < (cnt + 7) / 8; ++j8)
            D.d[u++] = (uint32_t)((D2OFF + 8 * j8) * 2) | ((uint32_t)((1 + f) * 2) << 16);
    }
    while (u < NDESC) D.d[u++] = 0u;                   // pad: t[0..7] * xd[0]
    return D;
}
__device__ const Desc DESC_G = build_desc();

// Map new K index -> original monomial index (or -1 = zero W row).
struct Oldk { int16_t v[NSTEPS * 16]; };
constexpr Oldk build_oldk() {
    Oldk K{};
    int k = 0;
    for (int ti = 0; ti < 576; ++ti) {                 // segA
        int old;
        if (ti == 0) old = 0;
        else if (ti <= 32) old = ti;
        else if (ti >= D2OFF && ti < D2OFF + D2N) old = 33 + (ti - D2OFF);
        else old = -1;
        K.v[k++] = (int16_t)old;
    }
    for (int f = 0; f < NF; ++f) {                     // segB
        int cnt = (f + 1) * (f + 2) / 2;
        int off3 = 0;
        for (int g = 0; g < f; ++g) off3 += (g + 1) * (g + 2) / 2;
        int oc = (cnt + 7) / 8;
        for (int m = 0; m < oc * 8; ++m)
            K.v[k++] = (int16_t)(m < cnt ? 561 + off3 + m : -1);
    }
    while (k < NSTEPS * 16) K.v[k++] = (int16_t)-1;    // pad steps: zero W
    return K;
}
__device__ const Oldk OLDK_G = build_oldk();

// ---- phase-1 helpers ----
template<int TI>
__device__ __forceinline__ _Float16 tval(const float (&xr)[NF]) {
    if constexpr (TI == 0) return (_Float16)1.0f;
    else if constexpr (TI >= 1 && TI <= 32) return (_Float16)xr[TI - 1];
    else if constexpr (TI >= D2OFF && TI < D2OFF + D2N) {
        constexpr int m = TI - D2OFF;
        return (_Float16)(xr[D2T.a[m]] * xr[D2T.b[m]]);
    } else return (_Float16)0.0f;
}

template<int O, int... Js>
__device__ __forceinline__ void put_oct(std::integer_sequence<int, Js...>,
                                        const float (&xr)[NF], _Float16* trow, int r) {
    f16x8 v = { tval<O * 8 + Js>(xr)... };
    int slot = (O & ~7) | ((O ^ r) & 7);               // XOR swizzle (16B granule)
    *(f16x8*)(trow + slot * 8) = v;
}

template<int BASE, int... Os>
__device__ __forceinline__ void p1_octs(std::integer_sequence<int, Os...>,
                                        const float (&xr)[NF], _Float16* trow, int r) {
    (put_oct<BASE + Os>(std::make_integer_sequence<int, 8>{}, xr, trow, r), ...);
}

template<int V>
__device__ __forceinline__ void xdw(const float (&xr)[NF], _Float16* xdrow) {
    if constexpr (V == 0) xdrow[0] = (_Float16)1.0f;
    else if constexpr (V <= 32) xdrow[V] = (_Float16)xr[V - 1];
}

template<int G>
__device__ __forceinline__ void p1_group(const float (&xr)[NF], _Float16* trow,
                                         _Float16* xdrow, int r) {
    if constexpr (G < 8)
        p1_octs<G * 5>(std::make_integer_sequence<int, 5>{}, xr, trow, r);
    else
        p1_octs<40 + (G - 8) * 4>(std::make_integer_sequence<int, 4>{}, xr, trow, r);
    xdw<2 * G>(xr, xdrow);
    xdw<2 * G + 1>(xr, xdrow);
    if constexpr (G == 15) xdw<32>(xr, xdrow);
}

// ---- prep: Wh = permuted/padded f16 W ([step][64 lanes][8]) ----
__global__ void prep(const float* __restrict__ W, _Float16* __restrict__ Wh) {
    int id = blockIdx.x * 256 + threadIdx.x;           // 112*256 = 28672 octets
    int step = id >> 6, rem = id & 63, hs = rem >> 5, n = rem & 31;
    int k0 = step * 16 + hs * 8;
    short8v olds = *(const short8v*)(OLDK_G.v + k0);   // one 16B load
    f16x8 v;
#pragma unroll
    for (int j = 0; j < 8; ++j) {
        int old = olds[j];
        v[j] = (_Float16)(old >= 0 ? W[old * 32 + n] : 0.0f);
    }
    *(f16x8*)(Wh + (size_t)id * 8) = v;
}

__global__ __launch_bounds__(512, 2) void gemm(const float* __restrict__ x,
                                               const _Float16* __restrict__ Wh,
                                               float* __restrict__ out) {
    __shared__ __align__(16) unsigned char smem[SMEM_BYTES];
    _Float16* t  = (_Float16*)smem;
    _Float16* xd = (_Float16*)(smem + XD_OFF);

    const int tid = threadIdx.x;
    const int wave = __builtin_amdgcn_readfirstlane(tid >> 6);
    const int lane = tid & 63;
    const int hsel = lane >> 5, r = lane & 31;
    const int mtile = blockIdx.x;

    // ---- phase 1: t (swizzled) + xdup ----
    {
        const int pr = tid & 31, g = tid >> 5;         // 16 workers per row
        float xr[NF];
        const float4* xp = (const float4*)(x + (size_t)(mtile * 32 + pr) * NF);
#pragma unroll
        for (int i = 0; i < 8; ++i) {
            float4 v = xp[i];
            xr[4 * i + 0] = v.x; xr[4 * i + 1] = v.y;
            xr[4 * i + 2] = v.z; xr[4 * i + 3] = v.w;
        }
        _Float16* trow = t + pr * TSTRIDE;
        _Float16* xdrow = xd + pr * XDSTRIDE;
        switch (g) {
            case  0: p1_group< 0>(xr, trow, xdrow, pr); break;
            case  1: p1_group< 1>(xr, trow, xdrow, pr); break;
            case  2: p1_group< 2>(xr, trow, xdrow, pr); break;
            case  3: p1_group< 3>(xr, trow, xdrow, pr); break;
            case  4: p1_group< 4>(xr, trow, xdrow, pr); break;
            case  5: p1_group< 5>(xr, trow, xdrow, pr); break;
            case  6: p1_group< 6>(xr, trow, xdrow, pr); break;
            case  7: p1_group< 7>(xr, trow, xdrow, pr); break;
            case  8: p1_group< 8>(xr, trow, xdrow, pr); break;
            case  9: p1_group< 9>(xr, trow, xdrow, pr); break;
            case 10: p1_group<10>(xr, trow, xdrow, pr); break;
            case 11: p1_group<11>(xr, trow, xdrow, pr); break;
            case 12: p1_group<12>(xr, trow, xdrow, pr); break;
            case 13: p1_group<13>(xr, trow, xdrow, pr); break;
            case 14: p1_group<14>(xr, trow, xdrow, pr); break;
            default: p1_group<15>(xr, trow, xdrow, pr); break;
        }
    }

    // ---- per-wave descriptor preload (lane = step - s0; indices 0..63 used) ----
    const int s0 = __builtin_amdgcn_readfirstlane(wave * CHUNK);
    uint32_t vD0 = DESC_G.d[2 * (s0 + lane)];          // max idx 2*(392+63)=910 < 1024
    uint32_t vD1 = DESC_G.d[2 * (s0 + lane) + 1];

    __syncthreads();

    const char* trowB = (const char*)t + r * (TSTRIDE * 2);
    const char* xdrowB = (const char*)xd + r * (XDSTRIDE * 2);
    const char* wpB = (const char*)Wh + lane * 16;     // + s*1024 per step
    const uint32_t rx = (uint32_t)((r & 7) << 4);

    f32x16 acc0, acc1;
#pragma unroll
    for (int i = 0; i < 16; ++i) { acc0[i] = 0.0f; acc1[i] = 0.0f; }

#define DSEL(IDX) (hsel ? __builtin_amdgcn_readlane(vD1, (IDX)) \
                        : __builtin_amdgcn_readlane(vD0, (IDX)))

    f16x8 araw0, araw1, araw2, araw3, araw4, araw5, araw6, araw7;
    f16x8 breg0, breg1, breg2, breg3, breg4, breg5, breg6, breg7;
    _Float16 xs0, xs1, xs2, xs3, xs4, xs5, xs6, xs7;

#define LOADSLOT(P, IDX) do {                                                 \
    uint32_t d_ = DSEL(IDX);                                                  \
    araw##P = *(const f16x8*)(trowB + ((d_ & 0xffffu) ^ rx));                 \
    xs##P   = *(const _Float16*)(xdrowB + (d_ >> 16));                        \
    breg##P = *(const f16x8*)(wpB + (size_t)(s0 + (IDX)) * 1024);             \
} while (0)

    LOADSLOT(0, 0); LOADSLOT(1, 1); LOADSLOT(2, 2); LOADSLOT(3, 3);
    LOADSLOT(4, 4); LOADSLOT(5, 5); LOADSLOT(6, 6); LOADSLOT(7, 7);

#define BODY(P, IDX, A) do {                                                  \
    f16x8 xsv_ = { xs##P, xs##P, xs##P, xs##P, xs##P, xs##P, xs##P, xs##P };  \
    f16x8 a_ = araw##P * xsv_;                                                \
    f16x8 bu_ = breg##P;                                                      \
    LOADSLOT(P, (IDX) + 8);  /* prefetch 8 ahead; pads/over-reads are safe */ \
    A = __builtin_amdgcn_mfma_f32_32x32x16_f16(a_, bu_, A, 0, 0, 0);          \
} while (0)

#pragma unroll
    for (int i = 0; i < 7; ++i) {
        BODY(0, 8 * i + 0, acc0);
        BODY(1, 8 * i + 1, acc1);
        BODY(2, 8 * i + 2, acc0);
        BODY(3, 8 * i + 3, acc1);
        BODY(4, 8 * i + 4, acc0);
        BODY(5, 8 * i + 5, acc1);
        BODY(6, 8 * i + 6, acc0);
        BODY(7, 8 * i + 7, acc1);
    }
#undef BODY
#undef LOADSLOT
#undef DSEL

#pragma unroll
    for (int i = 0; i < 16; ++i) acc0[i] += acc1[i];

    // ---- epilogue: 8-bank LDS reduce (aliased over t), add x, plain store ----
    __syncthreads();                                   // all waves done with t/xd
    float* red = (float*)smem;                         // 8 * 4096 B = 32768 B
    float* bank = red + wave * 1024;
#pragma unroll
    for (int reg = 0; reg < 16; ++reg) {
        int rr = (reg & 3) + 8 * (reg >> 2) + 4 * hsel;  // C/D row
        bank[rr * 32 + r] = acc0[reg];
    }
    __syncthreads();
    const float* xt = x + (size_t)mtile * 1024;
    float* op = out + (size_t)mtile * 1024;
#pragma unroll
    for (int i = 0; i < 2; ++i) {
        int e = tid + i * 512;
        float v = red[e] + red[1024 + e] + red[2048 + e] + red[3072 + e]
                + red[4096 + e] + red[5120 + e] + red[6144 + e] + red[7168 + e]
                + xt[e];
        op[e] = v;
    }
}

extern "C" void kernel_launch(void* const* d_in, const int* in_sizes, int n_in,
                              void* d_out, int out_size, void* d_ws, size_t ws_size,
                              hipStream_t stream) {
    (void)in_sizes; (void)n_in; (void)out_size; (void)ws_size;
    const float* x = (const float*)d_in[0];   // [8192,32]
    const float* W = (const float*)d_in[1];   // [6545,32]
    float* out = (float*)d_out;               // [8192,32]
    _Float16* Wh = (_Float16*)d_ws;           // ~467 KB of d_ws used (incl over-read)

    prep<<<112, 256, 0, stream>>>(W, Wh);
    gemm<<<256, 512, 0, stream>>>(x, Wh, out);
}